// Round 1
// baseline (86144.287 us; speedup 1.0000x reference)
//
#include <hip/hip_runtime.h>
#include <hip/hip_cooperative_groups.h>
#include <math.h>

namespace cg = cooperative_groups;

#define S   128
#define BB  24
#define RR  64
#define NT  256
#define MAXIT 100

// ---- per-block workspace layout (bytes) ----
#define OFF_PC     0          // 128*128 f32
#define OFF_OPT    65536
#define OFF_FEATS  131072
#define OFF_CAM    196608
#define OFF_MAT0   262144     // 128*128 f64
#define OFF_MAT1   393216
#define OFF_MPAR   524288     // 127 levels * 128 i16 (padded to 32768 each)
#define OFF_MOUT   557056
#define OFF_MCYC   589824
#define OFF_MBI    622592
#define OFF_MBO    655360
#define OFF_MHDR   688128     // 127 * 4 i32
#define PER_BLOCK  720896
#define OFF_TAIL   ((size_t)PER_BLOCK * BB)
// tail: objBuf[2][24] f64 (384B), accAdv f64 (+384), accData f64 (+392)

// =======================================================================
// Kernel A: feats / cam / data-term / pc init, all in transposed (d,h)
// space which equals the raw (b, j, i) input layout.
// =======================================================================
__global__ void prep_kernel(const float* __restrict__ s_arc,
                            const float* __restrict__ s_rel,
                            const int* __restrict__ arcs,
                            const int* __restrict__ rels,
                            char* __restrict__ ws) {
    int idx = blockIdx.x * blockDim.x + threadIdx.x;   // b*16384 + d*128 + h
    if (idx >= BB * S * S) return;
    int b  = idx >> 14;
    int dh = idx & (S * S - 1);
    int d  = dh >> 7;
    int h  = dh & (S - 1);

    float sa = s_arc[idx];
    const float* sr = s_rel + (size_t)idx * RR;
    int arc = arcs[b * S + d];
    int rel = rels[b * S + d];
    int rstar = (d >= 1 && h == arc) ? rel : -1;

    float fm = -INFINITY;          // feats = max_r comb
    float bestv = -INFINITY;       // penalized argmax (first-max)
    float camv = 0.f, datav = 0.f;
    for (int r = 0; r < RR; ++r) {
        float comb = __fadd_rn(sa, sr[r]);             // numpy f32 add
        if (comb > fm) fm = comb;
        float pen = (r == rstar) ? 0.0f : 1.0f;        // 1 - p_rel_data
        float v = __fadd_rn(pen, comb);
        if (v > bestv) { bestv = v; camv = comb; }     // np.argmax: strict >
        if (rstar >= 0 && r == rel) datav = comb;
    }

    char* base = ws + (size_t)b * PER_BLOCK;
    ((float*)(base + OFF_FEATS))[dh] = fm;
    ((float*)(base + OFF_CAM))[dh]   = camv;
    float pc0 = (d >= 1 && h == d - 1) ? 1.0f : 0.0f;  // initial chain
    ((float*)(base + OFF_PC))[dh]  = pc0;
    ((float*)(base + OFF_OPT))[dh] = pc0;

    if (rstar >= 0) {
        double* accData = (double*)(ws + OFF_TAIL + 392);
        atomicAdd(accData, (double)datav);
    }
}

// =======================================================================
// CLE: min-cost arborescence rooted at 0, faithful to the numpy reference
// (first-index tie-breaks, serial coloring cycle-find, f64 internals).
// Matrices col-major: C[h][d] = cur[d*S + h]; result is parent vector.
// =======================================================================
__device__ void cle_run(int mode, const float* pcT, const float* featsT,
                        const int* phat,
                        double* mat0, double* mat1,
                        short* mPar, short* mOut, short* mCyc,
                        short* mBI, short* mBO, int* mHdr,
                        int* shPar, int* shCyc, int* shOut, int* shTmp,
                        signed char* shColor, short* shPath,
                        double* shCycCost, int* shScal,
                        int* resPar, int* resTmp)
{
    const int tid = threadIdx.x;
    // level-0 matrix: diag & col0 = inf (reference fill_diagonal / C[:,0]=inf)
    for (int idx = tid; idx < S * S; idx += NT) {
        int d = idx >> 7, h = idx & (S - 1);
        double v;
        if (h == d || d == 0) v = (double)INFINITY;
        else if (mode == 0) v = -(double)pcT[idx];
        else {
            float ph = (phat[d] == h) ? 1.0f : 0.0f;
            float g = __fdiv_rn(__fsub_rn(ph, featsT[idx]), 24.0f); // grad f32
            v = (double)g;
        }
        mat0[idx] = v;
    }
    __syncthreads();

    int lvl = 0, n = S;
    while (true) {
        double* cur = (lvl & 1) ? mat1 : mat0;
        // par[d] = argmin_h C[h][d], first-min
        if (tid == 0) shPar[0] = -1;
        else if (tid < n) {
            const double* col = cur + tid * S;
            double bv = col[0]; int bi = 0;
            for (int hh = 1; hh < n; ++hh) {
                double v = col[hh];
                if (v < bv) { bv = v; bi = hh; }
            }
            shPar[tid] = bi;
        }
        __syncthreads();
        // serial cycle find (exact _find_cycle order)
        if (tid == 0) {
            for (int i = 0; i < n; ++i) shColor[i] = 0;
            int clen = 0;
            for (int s = 1; s < n && clen == 0; ++s) {
                if (shColor[s]) continue;
                int plen = 0, v = s;
                while (v != -1 && shColor[v] == 0) {
                    shColor[v] = 1; shPath[plen] = (short)v; shTmp[v] = plen;
                    ++plen; v = shPar[v];
                }
                if (v != -1 && shColor[v] == 1) {
                    int st = shTmp[v];
                    clen = plen - st;
                    for (int i = 0; i < clen; ++i) shCyc[i] = shPath[st + i];
                }
                for (int i = 0; i < plen; ++i) shColor[shPath[i]] = 2;
            }
            shScal[0] = clen;
            shScal[2] = lvl;
        }
        __syncthreads();
        int clen = shScal[0];
        if (clen == 0) {
            if (tid < n) resPar[tid] = shPar[tid];
            __syncthreads();
            break;
        }
        // in_cyc flags + out[] (ascending)
        if (tid < n) shColor[tid] = 0;
        __syncthreads();
        if (tid < clen) shColor[shCyc[tid]] = 1;
        __syncthreads();
        if (tid == 0) {
            int k = 0;
            for (int v2 = 0; v2 < n; ++v2) if (!shColor[v2]) shOut[k++] = v2;
            shScal[1] = k;
        }
        __syncthreads();
        int k = shScal[1];
        // cycle parent-edge costs + save metadata
        if (tid < clen) {
            int c = shCyc[tid];
            shCycCost[tid] = cur[c * S + shPar[c]];
            mCyc[lvl * S + tid] = (short)c;
        }
        if (tid < n) mPar[lvl * S + tid] = (short)shPar[tid];
        if (tid < k) mOut[lvl * S + tid] = (short)shOut[tid];
        if (tid == 0) {
            mHdr[lvl * 4] = n; mHdr[lvl * 4 + 1] = k; mHdr[lvl * 4 + 2] = clen;
        }
        __syncthreads();
        // build contracted matrix (size k+1, sup = k)
        double* nxt = (lvl & 1) ? mat0 : mat1;
        for (int idx = tid; idx < k * k; idx += NT) {
            int di = idx / k, hi = idx - di * k;
            nxt[di * S + hi] = (hi == di || di == 0)
                ? (double)INFINITY : cur[shOut[di] * S + shOut[hi]];
        }
        if (tid < k) {   // enter: per out-row, argmin over cycle (first-min)
            int oh = shOut[tid];
            double bv = cur[shCyc[0] * S + oh] - shCycCost[0]; int bi = 0;
            for (int ci = 1; ci < clen; ++ci) {
                double v = cur[shCyc[ci] * S + oh] - shCycCost[ci];
                if (v < bv) { bv = v; bi = ci; }
            }
            mBI[lvl * S + tid] = (short)bi;
            nxt[k * S + tid] = bv;
        }
        if (tid < k) {   // exit: per out-col, argmin over cycle (first-min)
            double bv; int bo = 0;
            if (shOut[tid] == 0) bv = (double)INFINITY;  // col0 = inf
            else {
                const double* colc = cur + shOut[tid] * S;
                bv = colc[shCyc[0]];
                for (int ci = 1; ci < clen; ++ci) {
                    double v = colc[shCyc[ci]];
                    if (v < bv) { bv = v; bo = ci; }
                }
            }
            mBO[lvl * S + tid] = (short)bo;
            nxt[tid * S + k] = bv;
        }
        if (tid == 0) nxt[k * S + k] = (double)INFINITY;
        __syncthreads();
        n = k + 1;
        ++lvl;
    }
    // unwind: expand parent vectors level by level
    int deepest = shScal[2];
    int* child = resPar; int* curp = resTmp;
    for (int l = deepest - 1; l >= 0; --l) {
        int kl = mHdr[l * 4 + 1], cl = mHdr[l * 4 + 2];
        const short* Mp = mPar + l * S; const short* Mo = mOut + l * S;
        const short* Mc = mCyc + l * S;
        const short* Bi = mBI + l * S; const short* Bo = mBO + l * S;
        if (tid == 0) {
            int hiSup = child[kl];          // parent of supernode
            shScal[3] = Mo[hiSup];          // u
            shScal[4] = Mc[Bi[hiSup]];      // v (cycle entry)
            curp[0] = -1;
        }
        __syncthreads();
        int u = shScal[3], v = shScal[4];
        if (tid >= 1 && tid < kl) {
            int hi = child[tid];
            curp[Mo[tid]] = (hi == kl) ? (int)Mc[Bo[tid]] : (int)Mo[hi];
        }
        if (tid < cl) {
            int c = Mc[tid];
            curp[c] = (c == v) ? u : (int)Mp[c];
        }
        __syncthreads();
        int* t2 = child; child = curp; curp = t2;
    }
    if (child != resPar) { if (tid < S) resPar[tid] = child[tid]; }
    __syncthreads();
}

__device__ __forceinline__ double blockReduce(double v, double* shRed) {
    for (int o = 32; o > 0; o >>= 1) v += __shfl_down(v, o, 64);
    int lane = threadIdx.x & 63, w = threadIdx.x >> 6;
    if (lane == 0) shRed[w] = v;
    __syncthreads();
    double r = 0.0;
    if (threadIdx.x == 0)
        for (int i = 0; i < NT / 64; ++i) r += shRed[i];
    return r;   // valid on thread 0 only
}

// =======================================================================
// Cooperative FW kernel: 24 blocks (one per batch), 100 iterations,
// one grid.sync per iteration (all blocks redundantly track `best`).
// =======================================================================
__global__ void __launch_bounds__(NT) fw_kernel(char* __restrict__ ws,
                                                float* __restrict__ d_out) {
    cg::grid_group grid = cg::this_grid();
    const int b = blockIdx.x, tid = threadIdx.x;
    char* base = ws + (size_t)b * PER_BLOCK;
    float* pcT   = (float*)(base + OFF_PC);
    float* optT  = (float*)(base + OFF_OPT);
    const float* featsT = (const float*)(base + OFF_FEATS);
    const float* camT   = (const float*)(base + OFF_CAM);
    double* mat0 = (double*)(base + OFF_MAT0);
    double* mat1 = (double*)(base + OFF_MAT1);
    short* mPar = (short*)(base + OFF_MPAR);
    short* mOut = (short*)(base + OFF_MOUT);
    short* mCyc = (short*)(base + OFF_MCYC);
    short* mBI  = (short*)(base + OFF_MBI);
    short* mBO  = (short*)(base + OFF_MBO);
    int*   mHdr = (int*)(base + OFF_MHDR);
    double* objBuf  = (double*)(ws + OFF_TAIL);
    double* accAdv  = (double*)(ws + OFF_TAIL + 384);
    double* accData = (double*)(ws + OFF_TAIL + 392);

    __shared__ int shPar[S], shCyc[S], shOut[S], shTmp[S];
    __shared__ signed char shColor[S];
    __shared__ short shPath[S];
    __shared__ double shCycCost[S];
    __shared__ int shScal[8];
    __shared__ int shPhat[S], shSpar[S], shRes2[S];
    __shared__ double shRed[NT / 64];

    double best = (double)INFINITY;

    for (int t = 0; t < MAXIT; ++t) {
        // p_hat = mst(-pc)
        cle_run(0, pcT, featsT, (const int*)0, mat0, mat1,
                mPar, mOut, mCyc, mBI, mBO, mHdr,
                shPar, shCyc, shOut, shTmp, shColor, shPath, shCycCost, shScal,
                shPhat, shRes2);
        // obj_b = sum((p_hat - feats) * pc)   (f32 products, f64 accumulate)
        double part = 0.0;
        for (int idx = tid; idx < S * S; idx += NT) {
            int d = idx >> 7, h = idx & (S - 1);
            float ph = (shPhat[d] == h) ? 1.0f : 0.0f;
            float prod = __fmul_rn(__fsub_rn(ph, featsT[idx]), pcT[idx]);
            part += (double)prod;
        }
        __syncthreads();
        double tot = blockReduce(part, shRed);
        if (tid == 0)
            __hip_atomic_store(&objBuf[(t & 1) * BB + b], tot,
                               __ATOMIC_RELEASE, __HIP_MEMORY_SCOPE_AGENT);
        grid.sync();
        // every block computes the identical global obj & best trajectory
        double obj = 0.0;
        for (int bb = 0; bb < BB; ++bb)
            obj += __hip_atomic_load(&objBuf[(t & 1) * BB + bb],
                                     __ATOMIC_ACQUIRE, __HIP_MEMORY_SCOPE_AGENT);
        obj /= (double)BB;
        if (obj < best) {
            best = obj;
            for (int idx = tid; idx < S * S; idx += NT) optT[idx] = pcT[idx];
        }
        // s = mst(grad)
        cle_run(1, pcT, featsT, shPhat, mat0, mat1,
                mPar, mOut, mCyc, mBI, mBO, mHdr,
                shPar, shCyc, shOut, shTmp, shColor, shPath, shCycCost, shScal,
                shSpar, shRes2);
        // pc += gamma * (s - pc)   (f32, no FMA contraction -> numpy-exact)
        float gamma = (float)(2.0 / (double)(t + 2));
        for (int idx = tid; idx < S * S; idx += NT) {
            int d = idx >> 7, h = idx & (S - 1);
            float sv = (shSpar[d] == h) ? 1.0f : 0.0f;
            float p = pcT[idx];
            pcT[idx] = __fadd_rn(p, __fmul_rn(gamma, __fsub_rn(sv, p)));
        }
    }
    // loss partial: sum(opt * cam)
    double part = 0.0;
    for (int idx = tid; idx < S * S; idx += NT) {
        float prod = __fmul_rn(optT[idx], camT[idx]);
        part += (double)prod;
    }
    __syncthreads();
    double tot = blockReduce(part, shRed);
    if (tid == 0) atomicAdd(accAdv, tot);
    grid.sync();
    if (b == 0 && tid == 0) {
        double adv = __hip_atomic_load(accAdv, __ATOMIC_ACQUIRE,
                                       __HIP_MEMORY_SCOPE_AGENT);
        double dat = *accData;
        d_out[0] = (float)((adv - dat) / (double)BB);
    }
}

extern "C" void kernel_launch(void* const* d_in, const int* in_sizes, int n_in,
                              void* d_out, int out_size, void* d_ws, size_t ws_size,
                              hipStream_t stream) {
    const float* s_arc = (const float*)d_in[0];
    const float* s_rel = (const float*)d_in[1];
    const int*   arcs  = (const int*)d_in[2];
    const int*   rels  = (const int*)d_in[3];
    char* ws = (char*)d_ws;

    hipMemsetAsync(ws + OFF_TAIL, 0, 512, stream);
    int total = BB * S * S;
    prep_kernel<<<(total + NT - 1) / NT, NT, 0, stream>>>(s_arc, s_rel, arcs, rels, ws);

    char* wsArg = ws;
    float* outArg = (float*)d_out;
    void* kargs[] = { (void*)&wsArg, (void*)&outArg };
    hipLaunchCooperativeKernel(fw_kernel, dim3(BB), dim3(NT), kargs, 0, stream);
}

// Round 2
// 51801.648 us; speedup vs baseline: 1.6630x; 1.6630x over previous
//
#include <hip/hip_runtime.h>
#include <hip/hip_cooperative_groups.h>
#include <math.h>

namespace cg = cooperative_groups;

#define S     128
#define STR   129       // LDS matrix column stride (f64) - 4-way bank spread
#define BB    24
#define RR    64
#define MAXIT 100

// ---- per-block workspace layout (bytes) ----
#define OFF_PC     0          // 128*128 f32
#define OFF_OPT    65536
#define OFF_FEATS  131072
#define OFF_CAM    196608
#define OFF_MOUT   262144     // 128 levels * 128 int : new-index -> old-index
#define OFF_MCYC   327680     // cycle node list (old index space), rotated
#define OFF_MENT   393216     // per out j: cyc[best_in[j]]  (resolved)
#define OFF_MEXO   458752     // per out j: cyc[best_out[j]] (resolved)
#define PER_BLOCK  524288
#define OFF_TAIL   ((size_t)PER_BLOCK * BB)
// tail: objBuf[2][24] f64 (384B), accAdv (+384), accData (+392)

// =======================================================================
// Kernel A: feats / cam / data-term / pc init (transposed (d,h) space ==
// raw input layout). Unchanged from validated round-1 kernel.
// =======================================================================
__global__ void prep_kernel(const float* __restrict__ s_arc,
                            const float* __restrict__ s_rel,
                            const int* __restrict__ arcs,
                            const int* __restrict__ rels,
                            char* __restrict__ ws) {
    int idx = blockIdx.x * blockDim.x + threadIdx.x;   // b*16384 + d*128 + h
    if (idx >= BB * S * S) return;
    int b  = idx >> 14;
    int dh = idx & (S * S - 1);
    int d  = dh >> 7;
    int h  = dh & (S - 1);

    float sa = s_arc[idx];
    const float* sr = s_rel + (size_t)idx * RR;
    int arc = arcs[b * S + d];
    int rel = rels[b * S + d];
    int rstar = (d >= 1 && h == arc) ? rel : -1;

    float fm = -INFINITY;
    float bestv = -INFINITY;
    float camv = 0.f, datav = 0.f;
    for (int r = 0; r < RR; ++r) {
        float comb = __fadd_rn(sa, sr[r]);
        if (comb > fm) fm = comb;
        float pen = (r == rstar) ? 0.0f : 1.0f;
        float v = __fadd_rn(pen, comb);
        if (v > bestv) { bestv = v; camv = comb; }
        if (rstar >= 0 && r == rel) datav = comb;
    }

    char* base = ws + (size_t)b * PER_BLOCK;
    ((float*)(base + OFF_FEATS))[dh] = fm;
    ((float*)(base + OFF_CAM))[dh]   = camv;
    float pc0 = (d >= 1 && h == d - 1) ? 1.0f : 0.0f;
    ((float*)(base + OFF_PC))[dh]  = pc0;
    ((float*)(base + OFF_OPT))[dh] = pc0;

    if (rstar >= 0) {
        double* accData = (double*)(ws + OFF_TAIL + 392);
        atomicAdd(accData, (double)datav);
    }
}

// =======================================================================
// Single-wave CLE state (LDS). mat is col-major: C[h][d] = mat[d*STR + h],
// indices are PHYSICAL slots; curOrd maps current node index -> slot.
// =======================================================================
struct ShState {
    double mat[S * STR];                 // 132096 B
    double entv[S], exv[S], cyccost[S];  // 3 KB
    int parIdx[S], parNew[S], curOrd[S], ordNew[S], o2n[S], outIdx[S],
        slotC[S], tmpCyc[S], inCyc[S], cycA[S], phat[S], spar[S], resA[S],
        hK[S], hC[S];                    // 7.5 KB
};

// Exact CLE (reference tie-breaks, f64 internals), single wave, no barriers.
__device__ void cle_run(int mode, const float* __restrict__ pcT,
                        const float* __restrict__ featsT, ShState* sh,
                        int* __restrict__ mOut, int* __restrict__ mCyc,
                        int* __restrict__ mEnt, int* __restrict__ mExo,
                        int* __restrict__ res)
{
    const int lane = threadIdx.x;
    const double DINF = __builtin_inf();

    // ---- level-0 matrix fill (diag & col0 = inf) ----
    for (int i = 0; i < (S * S) / 64; ++i) {
        int idx = i * 64 + lane;
        int d = idx >> 7, h = idx & (S - 1);
        double v;
        if (h == d || d == 0) v = DINF;
        else if (mode == 0) v = -(double)pcT[idx];
        else {
            float ph = (sh->phat[d] == h) ? 1.0f : 0.0f;
            v = (double)__fdiv_rn(__fsub_rn(ph, featsT[idx]), 24.0f);
        }
        sh->mat[d * STR + h] = v;
    }
    // ---- level-0 argmin per column (first-min) ----
#pragma unroll
    for (int s2 = 0; s2 < 2; ++s2) {
        int d = lane + s2 * 64;
        if (d == 0) sh->parIdx[0] = -1;
        else {
            const double* col = sh->mat + d * STR;
            double bv = col[0]; int bi = 0;
            for (int h = 1; h < S; ++h) {
                double v = col[h];
                if (v < bv) { bv = v; bi = h; }
            }
            sh->parIdx[d] = bi;
        }
        sh->curOrd[d] = d;
        sh->inCyc[d] = 0;
    }

    int n = S, lvl = 0;
    while (true) {
        // ---- cycle detection: pointer doubling in registers (bpermute) ----
        int j0 = (lane < n) ? sh->parIdx[lane] : -1;
        int j1 = (lane + 64 < n) ? sh->parIdx[lane + 64] : -1;
        int rounds = 0; while ((1 << rounds) < n) ++rounds;
        for (int r = 0; r < rounds; ++r) {
            int t0 = j0, t1 = j1;
            int a0 = __builtin_amdgcn_ds_bpermute((t0 & 63) * 4, j0);
            int b0 = __builtin_amdgcn_ds_bpermute((t0 & 63) * 4, j1);
            int a1 = __builtin_amdgcn_ds_bpermute((t1 & 63) * 4, j0);
            int b1 = __builtin_amdgcn_ds_bpermute((t1 & 63) * 4, j1);
            j0 = (t0 < 0) ? -1 : ((t0 < 64) ? a0 : b0);
            j1 = (t1 < 0) ? -1 : ((t1 < 64) ? a1 : b1);
        }
        unsigned long long m0 = __ballot(lane >= 1 && lane < n && j0 >= 0);
        unsigned long long m1 = __ballot(lane + 64 < n && j1 >= 0);
        if (m0 == 0 && m1 == 0) break;   // no cycle: done
        int sMin = m0 ? ((int)__ffsll(m0) - 1) : (64 + (int)__ffsll(m1) - 1);
        int c0 = (sMin < 64) ? __shfl(j0, sMin) : __shfl(j1, sMin - 64);

        // ---- enumerate cycle (all lanes redundant; lane0 stores) ----
        int L = 0, w = c0;
        do {
            if (lane == 0) { sh->tmpCyc[L] = w; sh->inCyc[w] = 1; }
            ++L;
            w = sh->parIdx[w];
        } while (w != c0);
        int e = sMin;                                   // entry node
        while (!sh->inCyc[e]) e = sh->parIdx[e];
        unsigned long long f0 = __ballot(lane < L && sh->tmpCyc[lane] == e);
        unsigned long long f1 = __ballot(lane + 64 < L && sh->tmpCyc[lane + 64] == e);
        int eIdx = f0 ? ((int)__ffsll(f0) - 1) : (64 + (int)__ffsll(f1) - 1);

        // rotated cycle list: cyc[i] = tmpCyc[(eIdx+i)%L]; par[cyc[i]]=cyc[i+1]
#pragma unroll
        for (int s2 = 0; s2 < 2; ++s2) {
            int i = lane + s2 * 64;
            if (i < L) {
                int pos = eIdx + i;  if (pos >= L) pos -= L;
                int pos2 = pos + 1;  if (pos2 >= L) pos2 -= L;
                int c  = sh->tmpCyc[pos];
                int cn = sh->tmpCyc[pos2];
                int sc = sh->curOrd[c];
                sh->cycA[i]  = c;
                sh->slotC[i] = sc;
                sh->cyccost[i] = sh->mat[sc * STR + sh->curOrd[cn]];
                mCyc[lvl * S + i] = c;
            }
        }

        // ---- out list (ascending) via ballot prefix; o2n renumber ----
        int ic0 = sh->inCyc[lane];
        int ic1 = sh->inCyc[lane + 64];
        unsigned long long g0 = __ballot(lane < n && !ic0);
        unsigned long long g1 = __ballot(lane + 64 < n && !ic1);
        int k = __popcll(g0) + __popcll(g1);
        unsigned long long lt = (1ull << lane) - 1ull;
        if (lane < n && !ic0) {
            int p = __popcll(g0 & lt);
            sh->outIdx[p] = lane; sh->o2n[lane] = p; mOut[lvl * S + p] = lane;
        }
        if (lane + 64 < n && !ic1) {
            int p = __popcll(g0) + __popcll(g1 & lt);
            sh->outIdx[p] = lane + 64; sh->o2n[lane + 64] = p; mOut[lvl * S + p] = lane + 64;
        }
        if (lane == 0) { sh->hK[lvl] = k; sh->hC[lvl] = L; }

        // ---- enter/exit (reads first, writes after: in-order DS pipe) ----
        int supSlot = sh->slotC[0];
        double ev[2], xv[2]; int so[2], np[2];
#pragma unroll
        for (int s2 = 0; s2 < 2; ++s2) {
            int j = lane + s2 * 64;
            ev[s2] = DINF; xv[s2] = DINF; so[s2] = 0; np[s2] = -3;
            if (j < k) {
                int d = sh->outIdx[j];
                int sd = sh->curOrd[d];
                so[s2] = sd;
                // enter: min over cyc of C[out_j, cyc_ci] - cyccost[ci]
                double bv = sh->mat[sh->slotC[0] * STR + sd] - sh->cyccost[0];
                int bi = 0;
                for (int ci = 1; ci < L; ++ci) {
                    double v = sh->mat[sh->slotC[ci] * STR + sd] - sh->cyccost[ci];
                    if (v < bv) { bv = v; bi = ci; }
                }
                ev[s2] = bv;
                sh->entv[j] = bv;
                mEnt[lvl * S + j] = sh->cycA[bi];
                // exit: min over cyc of C[cyc_ci, out_j]
                double b2 = sh->mat[sd * STR + sh->slotC[0]];
                int bo = 0;
                for (int ci = 1; ci < L; ++ci) {
                    double v = sh->mat[sd * STR + sh->slotC[ci]];
                    if (v < b2) { b2 = v; bo = ci; }
                }
                xv[s2] = b2;
                mExo[lvl * S + j] = sh->cycA[bo];
                sh->ordNew[j] = sd;
                // incremental par (exact; see proof in journal):
                if (j == 0) np[s2] = -1;
                else { int op = sh->parIdx[d]; np[s2] = sh->inCyc[op] ? -2 : sh->o2n[op]; }
            }
        }
        // write sup column/row into retired slot of cyc[0]
#pragma unroll
        for (int s2 = 0; s2 < 2; ++s2) {
            int j = lane + s2 * 64;
            if (j < k) {
                sh->mat[supSlot * STR + so[s2]] = ev[s2];
                sh->mat[so[s2] * STR + supSlot] = xv[s2];
            }
        }
        if (lane == 0) { sh->mat[supSlot * STR + supSlot] = DINF; sh->ordNew[k] = supSlot; }

        // sup column par: first-min over entv[0..k-1]
        double rv = (lane < k) ? sh->entv[lane] : DINF; int ri = lane;
        {
            double rv1 = (lane + 64 < k) ? sh->entv[lane + 64] : DINF;
            if (rv1 < rv) { rv = rv1; ri = lane + 64; }
        }
        for (int off = 32; off; off >>= 1) {
            double ov = __shfl_down(rv, off); int oi = __shfl_down(ri, off);
            if (ov < rv || (ov == rv && oi < ri)) { rv = ov; ri = oi; }
        }
        int supPar = __shfl(ri, 0);

#pragma unroll
        for (int s2 = 0; s2 < 2; ++s2) {
            int j = lane + s2 * 64;
            if (j < k) sh->parNew[j] = np[s2];
        }
        if (lane == 0) sh->parNew[k] = supPar;
        // rescan columns whose old par was in the cycle (exact recompute)
#pragma unroll
        for (int s2 = 0; s2 < 2; ++s2) {
            int j = lane + s2 * 64;
            if (j < k && np[s2] == -2) {
                int sd = so[s2];
                double bv = DINF; int bi = -1;
                for (int h2 = 0; h2 <= k; ++h2) {
                    double v = sh->mat[sd * STR + sh->ordNew[h2]];
                    if (v < bv) { bv = v; bi = h2; }
                }
                sh->parNew[j] = bi;
            }
        }
        // commit
#pragma unroll
        for (int s2 = 0; s2 < 2; ++s2) {
            int i = lane + s2 * 64;
            if (i <= k) { sh->parIdx[i] = sh->parNew[i]; sh->curOrd[i] = sh->ordNew[i]; }
            sh->inCyc[i] = 0;
        }
        n = k + 1; ++lvl;
    }

    // ---- unwind: expand parent vectors level by level ----
#pragma unroll
    for (int s2 = 0; s2 < 2; ++s2) {
        int i = lane + s2 * 64;
        res[i] = sh->parIdx[i];
    }
    for (int l = lvl - 1; l >= 0; --l) {
        int kl = sh->hK[l], cl = sh->hC[l];
        int hiSup = res[kl];
        int u  = mOut[l * S + hiSup];     // broadcast global reads
        int vE = mEnt[l * S + hiSup];
        if (lane == 0) sh->resA[0] = -1;
#pragma unroll
        for (int s2 = 0; s2 < 2; ++s2) {
            int j = lane + s2 * 64;
            if (j >= 1 && j < kl) {
                int hi = res[j];
                int dest = mOut[l * S + j];
                sh->resA[dest] = (hi == kl) ? mExo[l * S + j] : mOut[l * S + hi];
            }
            if (j < cl) {
                int c = mCyc[l * S + j];
                int pn = (j + 1 < cl) ? mCyc[l * S + j + 1] : mCyc[l * S];
                sh->resA[c] = (c == vE) ? u : pn;
            }
        }
#pragma unroll
        for (int s2 = 0; s2 < 2; ++s2) {
            int i = lane + s2 * 64;
            res[i] = sh->resA[i];
        }
    }
}

// =======================================================================
// Cooperative FW kernel: 24 blocks x 64 threads (one wave per batch item),
// one grid.sync per iteration; every block redundantly tracks `best`.
// =======================================================================
__global__ void __launch_bounds__(64) fw_kernel(char* __restrict__ ws,
                                                float* __restrict__ d_out) {
    cg::grid_group grid = cg::this_grid();
    const int b = blockIdx.x, lane = threadIdx.x;
    char* base = ws + (size_t)b * PER_BLOCK;
    float* pcT   = (float*)(base + OFF_PC);
    float* optT  = (float*)(base + OFF_OPT);
    const float* featsT = (const float*)(base + OFF_FEATS);
    const float* camT   = (const float*)(base + OFF_CAM);
    int* mOut = (int*)(base + OFF_MOUT);
    int* mCyc = (int*)(base + OFF_MCYC);
    int* mEnt = (int*)(base + OFF_MENT);
    int* mExo = (int*)(base + OFF_MEXO);
    double* objBuf  = (double*)(ws + OFF_TAIL);
    double* accAdv  = (double*)(ws + OFF_TAIL + 384);
    double* accData = (double*)(ws + OFF_TAIL + 392);

    __shared__ ShState sh;

    double best = __builtin_inf();
    for (int t = 0; t < MAXIT; ++t) {
        // p_hat = mst(-pc)
        cle_run(0, pcT, featsT, &sh, mOut, mCyc, mEnt, mExo, sh.phat);
        // obj_b = sum((p_hat - feats) * pc)   (f32 products, f64 accumulate)
        double part = 0.0;
        for (int i = 0; i < (S * S) / 64; ++i) {
            int idx = i * 64 + lane;
            int d = idx >> 7, h = idx & (S - 1);
            float ph = (sh.phat[d] == h) ? 1.0f : 0.0f;
            part += (double)__fmul_rn(__fsub_rn(ph, featsT[idx]), pcT[idx]);
        }
        for (int off = 32; off; off >>= 1) part += __shfl_down(part, off);
        if (lane == 0)
            __hip_atomic_store(&objBuf[(t & 1) * BB + b], part,
                               __ATOMIC_RELEASE, __HIP_MEMORY_SCOPE_AGENT);
        grid.sync();
        double obj = 0.0;
        for (int bb = 0; bb < BB; ++bb)
            obj += __hip_atomic_load(&objBuf[(t & 1) * BB + bb],
                                     __ATOMIC_ACQUIRE, __HIP_MEMORY_SCOPE_AGENT);
        obj /= (double)BB;
        if (obj < best) {
            best = obj;
            for (int i = 0; i < (S * S) / 64; ++i) {
                int idx = i * 64 + lane;
                optT[idx] = pcT[idx];
            }
        }
        // s = mst(grad)
        cle_run(1, pcT, featsT, &sh, mOut, mCyc, mEnt, mExo, sh.spar);
        // pc += gamma * (s - pc)   (f32, single-rounded ops: numpy-exact)
        float gamma = (float)(2.0 / (double)(t + 2));
        for (int i = 0; i < (S * S) / 64; ++i) {
            int idx = i * 64 + lane;
            int d = idx >> 7, h = idx & (S - 1);
            float sv = (sh.spar[d] == h) ? 1.0f : 0.0f;
            float p = pcT[idx];
            pcT[idx] = __fadd_rn(p, __fmul_rn(gamma, __fsub_rn(sv, p)));
        }
    }
    // loss partial: sum(opt * cam)
    double part = 0.0;
    for (int i = 0; i < (S * S) / 64; ++i) {
        int idx = i * 64 + lane;
        part += (double)__fmul_rn(optT[idx], camT[idx]);
    }
    for (int off = 32; off; off >>= 1) part += __shfl_down(part, off);
    if (lane == 0) atomicAdd(accAdv, part);
    grid.sync();
    if (b == 0 && lane == 0) {
        double adv = __hip_atomic_load(accAdv, __ATOMIC_ACQUIRE,
                                       __HIP_MEMORY_SCOPE_AGENT);
        double dat = __hip_atomic_load(accData, __ATOMIC_ACQUIRE,
                                       __HIP_MEMORY_SCOPE_AGENT);
        d_out[0] = (float)((adv - dat) / (double)BB);
    }
}

extern "C" void kernel_launch(void* const* d_in, const int* in_sizes, int n_in,
                              void* d_out, int out_size, void* d_ws, size_t ws_size,
                              hipStream_t stream) {
    const float* s_arc = (const float*)d_in[0];
    const float* s_rel = (const float*)d_in[1];
    const int*   arcs  = (const int*)d_in[2];
    const int*   rels  = (const int*)d_in[3];
    char* ws = (char*)d_ws;

    hipMemsetAsync(ws + OFF_TAIL, 0, 512, stream);
    int total = BB * S * S;
    prep_kernel<<<(total + 255) / 256, 256, 0, stream>>>(s_arc, s_rel, arcs, rels, ws);

    char* wsArg = ws;
    float* outArg = (float*)d_out;
    void* kargs[] = { (void*)&wsArg, (void*)&outArg };
    hipLaunchCooperativeKernel(fw_kernel, dim3(BB), dim3(64), kargs, 0, stream);
}

// Round 3
// 45157.812 us; speedup vs baseline: 1.9076x; 1.1471x over previous
//
#include <hip/hip_runtime.h>
#include <math.h>

#define S     128
#define STR   129       // LDS matrix column stride (f64)
#define BB    24
#define RR    64
#define MAXIT 100

// ---- per-block workspace layout (bytes) ----
#define OFF_PC     0          // 128*128 f32
#define OFF_FEATS  65536
#define OFF_CAM    131072
#define OFF_MOUT   196608     // 128 levels * 128 int : new-index -> old-index
#define OFF_MCYC   262144     // rotated cycle node list
#define OFF_MENT   327680     // per out j: cyc[best_in[j]]  (resolved)
#define OFF_MEXO   393216     // per out j: cyc[best_out[j]] (resolved)
#define PER_BLOCK  458752
#define OFF_OBJ    ((size_t)PER_BLOCK * BB)     // 24 * 128 * 8 = 24576
#define OFF_SPAR   (OFF_OBJ + 24576)            // 24 * 100 * 128 u8 = 307200
#define OFF_ACC    (OFF_SPAR + 307200)          // accAdv f64, accData f64

// =======================================================================
// Kernel A: feats / cam / data-term / pc init (transposed (d,h) space ==
// raw input layout). Logic identical to validated round-1/2 kernel.
// =======================================================================
__global__ void prep_kernel(const float* __restrict__ s_arc,
                            const float* __restrict__ s_rel,
                            const int* __restrict__ arcs,
                            const int* __restrict__ rels,
                            char* __restrict__ ws) {
    int idx = blockIdx.x * blockDim.x + threadIdx.x;   // b*16384 + d*128 + h
    if (idx >= BB * S * S) return;
    int b  = idx >> 14;
    int dh = idx & (S * S - 1);
    int d  = dh >> 7;
    int h  = dh & (S - 1);

    float sa = s_arc[idx];
    const float* sr = s_rel + (size_t)idx * RR;
    int arc = arcs[b * S + d];
    int rel = rels[b * S + d];
    int rstar = (d >= 1 && h == arc) ? rel : -1;

    float fm = -INFINITY;
    float bestv = -INFINITY;
    float camv = 0.f, datav = 0.f;
    for (int r = 0; r < RR; ++r) {
        float comb = __fadd_rn(sa, sr[r]);
        if (comb > fm) fm = comb;
        float pen = (r == rstar) ? 0.0f : 1.0f;
        float v = __fadd_rn(pen, comb);
        if (v > bestv) { bestv = v; camv = comb; }
        if (rstar >= 0 && r == rel) datav = comb;
    }

    char* base = ws + (size_t)b * PER_BLOCK;
    ((float*)(base + OFF_FEATS))[dh] = fm;
    ((float*)(base + OFF_CAM))[dh]   = camv;
    ((float*)(base + OFF_PC))[dh] = (d >= 1 && h == d - 1) ? 1.0f : 0.0f;

    if (rstar >= 0) {
        double* accData = (double*)(ws + OFF_ACC + 8);
        atomicAdd(accData, (double)datav);
    }
}

// =======================================================================
// Single-wave CLE state (LDS).
// =======================================================================
struct ShState {
    double mat[S * STR];            // 132096 B
    double cyccost[S];
    int parIdx[S], parNew[S], curOrd[S], ordNew[S], o2n[S], outIdx[S],
        slotC[S], inCyc[S], cycA[S], phat[S], spar[S], resA[S],
        hK[S], hC[S];
};

__device__ __forceinline__ int gather2(int lo, int hi, int idx) {
    int a = __builtin_amdgcn_ds_bpermute((idx & 63) * 4, lo);
    int b = __builtin_amdgcn_ds_bpermute((idx & 63) * 4, hi);
    return (idx & 64) ? b : a;
}

// Exact CLE (reference tie-breaks, f64 internals), single wave, no barriers.
__device__ void cle_run(int mode, const float* __restrict__ pcT,
                        const float* __restrict__ featsT, ShState* sh,
                        int* __restrict__ mOut, int* __restrict__ mCyc,
                        int* __restrict__ mEnt, int* __restrict__ mExo,
                        int* __restrict__ res)
{
    const int lane = threadIdx.x;
    const double DINF = __builtin_inf();

    // ---- level-0 matrix fill (diag & col0 = inf) ----
    for (int i = 0; i < (S * S) / 64; ++i) {
        int idx = i * 64 + lane;
        int d = idx >> 7, h = idx & (S - 1);
        double v;
        if (h == d || d == 0) v = DINF;
        else if (mode == 0) v = -(double)pcT[idx];
        else {
            float ph = (sh->phat[d] == h) ? 1.0f : 0.0f;
            v = (double)__fdiv_rn(__fsub_rn(ph, featsT[idx]), 24.0f);
        }
        sh->mat[d * STR + h] = v;
    }
    // ---- level-0 argmin per column (first-min) ----
#pragma unroll
    for (int s2 = 0; s2 < 2; ++s2) {
        int d = lane + s2 * 64;
        if (d == 0) sh->parIdx[0] = -1;
        else {
            const double* col = sh->mat + d * STR;
            double bv = col[0]; int bi = 0;
            for (int h = 1; h < S; ++h) {
                double v = col[h];
                if (v < bv) { bv = v; bi = h; }
            }
            sh->parIdx[d] = bi;
        }
        sh->curOrd[d] = d;
        sh->inCyc[d] = 0;
    }

    int n = S, lvl = 0;
    while (true) {
        // ---- pointer doubling, saving jump tables par^(2^r) ----
        int t0a[8], t1a[8];
        t0a[0] = sh->parIdx[lane];
        t1a[0] = sh->parIdx[lane + 64];
#pragma unroll
        for (int r = 0; r < 7; ++r) {
            int u0 = t0a[r], u1 = t1a[r];
            int g0 = gather2(t0a[r], t1a[r], u0 & 127);
            int g1 = gather2(t0a[r], t1a[r], u1 & 127);
            t0a[r + 1] = (u0 < 0) ? -1 : g0;
            t1a[r + 1] = (u1 < 0) ? -1 : g1;
        }
        int jf0 = t0a[7], jf1 = t1a[7];     // par^128 : -1 iff reaches root
        unsigned long long m0 = __ballot(lane >= 1 && lane < n && jf0 >= 0);
        unsigned long long m1 = __ballot(lane + 64 < n && jf1 >= 0);
        if (m0 == 0 && m1 == 0) break;   // no cycle: done
        int sMin = m0 ? ((int)__ffsll((unsigned long long)m0) - 1)
                      : (64 + (int)__ffsll((unsigned long long)m1) - 1);
        int c0 = (sMin < 64) ? __shfl(jf0, sMin) : __shfl(jf1, sMin - 64);

        // ---- dual parallel walk: w_l = par^l(sMin), v_l = par^l(c0) ----
        int w0 = sMin, w1 = sMin, v0 = c0, v1 = c0;
#pragma unroll
        for (int r = 0; r < 6; ++r) {
            int nw0 = gather2(t0a[r], t1a[r], w0);
            int nw1 = gather2(t0a[r], t1a[r], w1);
            int nv0 = gather2(t0a[r], t1a[r], v0);
            int nv1 = gather2(t0a[r], t1a[r], v1);
            bool bit = (lane >> r) & 1;
            w0 = bit ? nw0 : w0;  w1 = bit ? nw1 : w1;
            v0 = bit ? nv0 : v0;  v1 = bit ? nv1 : v1;
        }
        // set1 has l = lane+64: bit 6 always set
        w1 = gather2(t0a[6], t1a[6], w1);
        v1 = gather2(t0a[6], t1a[6], v1);

        // L = cycle length: first l>=1 with v_l == c0
        unsigned long long bl0 = __ballot(lane >= 1 && v0 == c0);
        unsigned long long bl1 = __ballot(v1 == c0);
        int L = bl0 ? ((int)__ffsll((unsigned long long)bl0) - 1)
                    : (64 + (int)__ffsll((unsigned long long)bl1) - 1);
        // mark cycle membership
        if (lane < L) sh->inCyc[v0 & 127] = 1;
        if (lane + 64 < L) sh->inCyc[v1 & 127] = 1;
        // p = entry distance on sMin's path; e = entry node
        int f0 = sh->inCyc[w0 & 127];
        int f1 = sh->inCyc[w1 & 127];
        unsigned long long pb0 = __ballot(f0 != 0);
        unsigned long long pb1 = __ballot(f1 != 0);
        int p = pb0 ? ((int)__ffsll((unsigned long long)pb0) - 1)
                    : (64 + (int)__ffsll((unsigned long long)pb1) - 1);
        int e = (p < 64) ? __shfl(w0, p) : __shfl(w1, p - 64);

        // rotated cycle list starting at e (reference order), slots, costs
        int nxg0 = gather2(w0, w1, lane + 1);
        int nxg1 = gather2(w0, w1, (lane + 65) & 127);
        {
            int l0 = lane;
            if (l0 >= p && l0 < p + L) {
                int i = l0 - p;
                int c = w0 & 127;
                int nn = (i + 1 < L) ? (nxg0 & 127) : e;
                int sc = sh->curOrd[c];
                sh->cycA[i] = c; sh->slotC[i] = sc;
                sh->cyccost[i] = sh->mat[sc * STR + sh->curOrd[nn]];
                mCyc[lvl * S + i] = c;
            }
            int l1 = lane + 64;
            if (l1 >= p && l1 < p + L) {
                int i = l1 - p;
                int c = w1 & 127;
                int nn = (i + 1 < L) ? (nxg1 & 127) : e;
                int sc = sh->curOrd[c];
                sh->cycA[i] = c; sh->slotC[i] = sc;
                sh->cyccost[i] = sh->mat[sc * STR + sh->curOrd[nn]];
                mCyc[lvl * S + i] = c;
            }
        }

        // ---- out list (ascending) via ballot prefix; o2n renumber ----
        int ic0 = sh->inCyc[lane];
        int ic1 = sh->inCyc[lane + 64];
        unsigned long long g0 = __ballot(lane < n && !ic0);
        unsigned long long g1 = __ballot(lane + 64 < n && !ic1);
        int k = __popcll(g0) + __popcll(g1);
        unsigned long long lt = (1ull << lane) - 1ull;
        if (lane < n && !ic0) {
            int pp = __popcll(g0 & lt);
            sh->outIdx[pp] = lane; sh->o2n[lane] = pp; mOut[lvl * S + pp] = lane;
        }
        if (lane + 64 < n && !ic1) {
            int pp = __popcll(g0) + __popcll(g1 & lt);
            sh->outIdx[pp] = lane + 64; sh->o2n[lane + 64] = pp; mOut[lvl * S + pp] = lane + 64;
        }
        if (lane == 0) { sh->hK[lvl] = k; sh->hC[lvl] = L; }

        // ---- enter/exit (reads first, writes after: in-order DS pipe) ----
        int supSlot = sh->slotC[0];
        double ev[2], xv[2]; int so[2], np[2];
#pragma unroll
        for (int s2 = 0; s2 < 2; ++s2) {
            int j = lane + s2 * 64;
            ev[s2] = DINF; xv[s2] = DINF; so[s2] = 0; np[s2] = -3;
            if (j < k) {
                int d = sh->outIdx[j];
                int sd = sh->curOrd[d];
                so[s2] = sd;
                // enter: min over cyc of C[out_j, cyc_ci] - cyccost[ci]
                double bv = sh->mat[sh->slotC[0] * STR + sd] - sh->cyccost[0];
                int bi = 0;
                for (int ci = 1; ci < L; ++ci) {
                    double v = sh->mat[sh->slotC[ci] * STR + sd] - sh->cyccost[ci];
                    if (v < bv) { bv = v; bi = ci; }
                }
                ev[s2] = bv;
                mEnt[lvl * S + j] = sh->cycA[bi];
                // exit: min over cyc of C[cyc_ci, out_j]
                double b2 = sh->mat[sd * STR + sh->slotC[0]];
                int bo = 0;
                for (int ci = 1; ci < L; ++ci) {
                    double v = sh->mat[sd * STR + sh->slotC[ci]];
                    if (v < b2) { b2 = v; bo = ci; }
                }
                xv[s2] = b2;
                mExo[lvl * S + j] = sh->cycA[bo];
                sh->ordNew[j] = sd;
                // incremental par (exact under enter>=colmin, validated R2)
                if (j == 0) np[s2] = -1;
                else { int op = sh->parIdx[d]; np[s2] = sh->inCyc[op] ? -2 : sh->o2n[op]; }
            }
        }
        // write sup column/row into retired slot of cyc[0]
#pragma unroll
        for (int s2 = 0; s2 < 2; ++s2) {
            int j = lane + s2 * 64;
            if (j < k) {
                sh->mat[supSlot * STR + so[s2]] = ev[s2];
                sh->mat[so[s2] * STR + supSlot] = xv[s2];
            }
        }
        if (lane == 0) { sh->mat[supSlot * STR + supSlot] = DINF; sh->ordNew[k] = supSlot; }

        // sup column par: first-min over ev[0..k-1]
        double rv = (lane < k) ? ev[0] : DINF; int ri = lane;
        {
            double rv1 = (lane + 64 < k) ? ev[1] : DINF;
            if (rv1 < rv) { rv = rv1; ri = lane + 64; }
        }
        for (int off = 32; off; off >>= 1) {
            double ov = __shfl_down(rv, off); int oi = __shfl_down(ri, off);
            if (ov < rv || (ov == rv && oi < ri)) { rv = ov; ri = oi; }
        }
        int supPar = __shfl(ri, 0);

#pragma unroll
        for (int s2 = 0; s2 < 2; ++s2) {
            int j = lane + s2 * 64;
            if (j < k) sh->parNew[j] = np[s2];
        }
        if (lane == 0) sh->parNew[k] = supPar;
        // rescan columns whose old par was in the cycle (exact recompute)
#pragma unroll
        for (int s2 = 0; s2 < 2; ++s2) {
            int j = lane + s2 * 64;
            if (j < k && np[s2] == -2) {
                int sd = so[s2];
                double bv = DINF; int bi = -1;
                for (int h2 = 0; h2 <= k; ++h2) {
                    double v = sh->mat[sd * STR + sh->ordNew[h2]];
                    if (v < bv) { bv = v; bi = h2; }
                }
                sh->parNew[j] = bi;
            }
        }
        // commit
#pragma unroll
        for (int s2 = 0; s2 < 2; ++s2) {
            int i = lane + s2 * 64;
            if (i <= k) { sh->parIdx[i] = sh->parNew[i]; sh->curOrd[i] = sh->ordNew[i]; }
            sh->inCyc[i] = 0;
        }
        n = k + 1; ++lvl;
    }

    // ---- unwind: register-pipelined, bpermute gathers ----
    int r0v = sh->parIdx[lane], r1v = sh->parIdx[lane + 64];
    int cmo0=0,cmo1=0,cme0=0,cme1=0,cmx0=0,cmx1=0,cmc0=0,cmc1=0;
    int l = lvl - 1;
    if (l >= 0) {
        cmo0 = mOut[l*S+lane]; cmo1 = mOut[l*S+lane+64];
        cme0 = mEnt[l*S+lane]; cme1 = mEnt[l*S+lane+64];
        cmx0 = mExo[l*S+lane]; cmx1 = mExo[l*S+lane+64];
        cmc0 = mCyc[l*S+lane]; cmc1 = mCyc[l*S+lane+64];
    }
    while (l >= 0) {
        int nmo0=0,nmo1=0,nme0=0,nme1=0,nmx0=0,nmx1=0,nmc0=0,nmc1=0;
        if (l >= 1) {
            nmo0 = mOut[(l-1)*S+lane]; nmo1 = mOut[(l-1)*S+lane+64];
            nme0 = mEnt[(l-1)*S+lane]; nme1 = mEnt[(l-1)*S+lane+64];
            nmx0 = mExo[(l-1)*S+lane]; nmx1 = mExo[(l-1)*S+lane+64];
            nmc0 = mCyc[(l-1)*S+lane]; nmc1 = mCyc[(l-1)*S+lane+64];
        }
        int kl = sh->hK[l], cl = sh->hC[l];
        int hiSup = gather2(r0v, r1v, kl);
        int u  = gather2(cmo0, cmo1, hiSup & 127);
        int vE = gather2(cme0, cme1, hiSup & 127);
        int gh0 = gather2(cmo0, cmo1, r0v & 127);
        int gh1 = gather2(cmo0, cmo1, r1v & 127);
        int gc0 = gather2(cmc0, cmc1, lane + 1);
        int gc1 = gather2(cmc0, cmc1, (lane + 65) & 127);
        int c00 = __shfl(cmc0, 0);
        if (lane == 0) sh->resA[0] = -1;
        if (lane >= 1 && lane < kl)
            sh->resA[cmo0 & 127] = (r0v == kl) ? cmx0 : gh0;
        if (lane + 64 < kl)
            sh->resA[cmo1 & 127] = (r1v == kl) ? cmx1 : gh1;
        if (lane < cl) {
            int c = cmc0;
            int pn = (lane + 1 < cl) ? gc0 : c00;
            sh->resA[c & 127] = (c == vE) ? u : pn;
        }
        if (lane + 64 < cl) {
            int c = cmc1;
            int pn = (lane + 65 < cl) ? gc1 : c00;
            sh->resA[c & 127] = (c == vE) ? u : pn;
        }
        r0v = sh->resA[lane]; r1v = sh->resA[lane + 64];
        cmo0=nmo0; cmo1=nmo1; cme0=nme0; cme1=nme1;
        cmx0=nmx0; cmx1=nmx1; cmc0=nmc0; cmc1=nmc1;
        --l;
    }
    res[lane] = r0v; res[lane + 64] = r1v;
}

// =======================================================================
// Free-running FW kernel: 24 independent blocks x 64 threads, no grid sync.
// Stores obj_b[t] and s-parent vectors for the finalize pass.
// =======================================================================
__global__ void __launch_bounds__(64) fw_kernel(char* __restrict__ ws) {
    const int b = blockIdx.x, lane = threadIdx.x;
    char* base = ws + (size_t)b * PER_BLOCK;
    float* pcT = (float*)(base + OFF_PC);
    const float* featsT = (const float*)(base + OFF_FEATS);
    int* mOut = (int*)(base + OFF_MOUT);
    int* mCyc = (int*)(base + OFF_MCYC);
    int* mEnt = (int*)(base + OFF_MENT);
    int* mExo = (int*)(base + OFF_MEXO);
    double* objG = (double*)(ws + OFF_OBJ) + (size_t)b * 128;
    unsigned char* sParG = (unsigned char*)(ws + OFF_SPAR) + (size_t)b * MAXIT * S;

    __shared__ ShState sh;

    for (int t = 0; t < MAXIT; ++t) {
        // p_hat = mst(-pc)
        cle_run(0, pcT, featsT, &sh, mOut, mCyc, mEnt, mExo, sh.phat);
        // obj_b = sum((p_hat - feats) * pc)  (f32 products, f64 accumulate)
        double part = 0.0;
        for (int i = 0; i < (S * S) / 64; ++i) {
            int idx = i * 64 + lane;
            int d = idx >> 7, h = idx & (S - 1);
            float ph = (sh.phat[d] == h) ? 1.0f : 0.0f;
            part += (double)__fmul_rn(__fsub_rn(ph, featsT[idx]), pcT[idx]);
        }
        for (int off = 32; off; off >>= 1) part += __shfl_down(part, off);
        if (lane == 0) objG[t] = part;
        // s = mst(grad)
        cle_run(1, pcT, featsT, &sh, mOut, mCyc, mEnt, mExo, sh.spar);
        sParG[t * S + lane]      = (unsigned char)(sh.spar[lane] & 255);
        sParG[t * S + lane + 64] = (unsigned char)(sh.spar[lane + 64] & 255);
        // pc += gamma * (s - pc)   (f32, single-rounded ops: numpy-exact)
        float gamma = (float)(2.0 / (double)(t + 2));
        for (int i = 0; i < (S * S) / 64; ++i) {
            int idx = i * 64 + lane;
            int d = idx >> 7, h = idx & (S - 1);
            float sv = (sh.spar[d] == h) ? 1.0f : 0.0f;
            float p2 = pcT[idx];
            pcT[idx] = __fadd_rn(p2, __fmul_rn(gamma, __fsub_rn(sv, p2)));
        }
    }
}

// =======================================================================
// Finalize: compute t* (first argmin of mean obj), replay pc to t*
// (bit-exact elementwise f32 recurrence), accumulate loss.
// =======================================================================
__global__ void __launch_bounds__(64) fin_kernel(char* __restrict__ ws) {
    const int b = blockIdx.x, lane = threadIdx.x;
    char* base = ws + (size_t)b * PER_BLOCK;
    const float* camT = (const float*)(base + OFF_CAM);
    const double* objG = (const double*)(ws + OFF_OBJ);
    const unsigned char* sParG =
        (const unsigned char*)(ws + OFF_SPAR) + (size_t)b * MAXIT * S;
    double* accAdv = (double*)(ws + OFF_ACC);

    __shared__ float pcL[S * S];
    __shared__ unsigned char sPL[MAXIT * S];

    // t* : running-min trajectory == first global argmin (strict <)
    double v0 = __builtin_inf(), v1 = __builtin_inf();
    if (lane < MAXIT) {
        double s = 0.0;
        for (int bb = 0; bb < BB; ++bb) s += objG[bb * 128 + lane];
        v0 = s / (double)BB;
    }
    if (lane + 64 < MAXIT) {
        double s = 0.0;
        for (int bb = 0; bb < BB; ++bb) s += objG[bb * 128 + lane + 64];
        v1 = s / (double)BB;
    }
    double bv = v0; int bi = lane;
    if (v1 < bv) { bv = v1; bi = lane + 64; }
    for (int off = 32; off; off >>= 1) {
        double ov = __shfl_down(bv, off); int oi = __shfl_down(bi, off);
        if (ov < bv || (ov == bv && oi < bi)) { bv = ov; bi = oi; }
    }
    int tStar = __shfl(bi, 0);

    // load s history
    for (int wgt = lane; wgt < (MAXIT * S) / 4; wgt += 64)
        ((unsigned int*)sPL)[wgt] = ((const unsigned int*)sParG)[wgt];

    // replay pc from chain to pc_{t*}
    for (int i = 0; i < (S * S) / 64; ++i) {
        int idx = i * 64 + lane;
        int d = idx >> 7, h = idx & (S - 1);
        pcL[idx] = (d >= 1 && h == d - 1) ? 1.0f : 0.0f;
    }
    for (int t = 0; t < tStar; ++t) {
        float gamma = (float)(2.0 / (double)(t + 2));
        for (int d = 0; d < S; ++d) {
            int sp = sPL[t * S + d];
            float p0 = pcL[d * S + lane];
            float p1 = pcL[d * S + lane + 64];
            float sv0 = (sp == lane) ? 1.0f : 0.0f;
            float sv1 = (sp == lane + 64) ? 1.0f : 0.0f;
            pcL[d * S + lane]      = __fadd_rn(p0, __fmul_rn(gamma, __fsub_rn(sv0, p0)));
            pcL[d * S + lane + 64] = __fadd_rn(p1, __fmul_rn(gamma, __fsub_rn(sv1, p1)));
        }
    }
    // loss partial: sum(opt * cam)
    double part = 0.0;
    for (int i = 0; i < (S * S) / 64; ++i) {
        int idx = i * 64 + lane;
        part += (double)__fmul_rn(pcL[idx], camT[idx]);
    }
    for (int off = 32; off; off >>= 1) part += __shfl_down(part, off);
    if (lane == 0) atomicAdd(accAdv, part);
}

__global__ void fin2_kernel(const char* __restrict__ ws, float* __restrict__ out) {
    if (threadIdx.x == 0) {
        const double* acc = (const double*)(ws + OFF_ACC);
        out[0] = (float)((acc[0] - acc[1]) / (double)BB);
    }
}

extern "C" void kernel_launch(void* const* d_in, const int* in_sizes, int n_in,
                              void* d_out, int out_size, void* d_ws, size_t ws_size,
                              hipStream_t stream) {
    const float* s_arc = (const float*)d_in[0];
    const float* s_rel = (const float*)d_in[1];
    const int*   arcs  = (const int*)d_in[2];
    const int*   rels  = (const int*)d_in[3];
    char* ws = (char*)d_ws;

    hipMemsetAsync(ws + OFF_ACC, 0, 16, stream);
    int total = BB * S * S;
    prep_kernel<<<(total + 255) / 256, 256, 0, stream>>>(s_arc, s_rel, arcs, rels, ws);
    fw_kernel<<<dim3(BB), dim3(64), 0, stream>>>(ws);
    fin_kernel<<<dim3(BB), dim3(64), 0, stream>>>(ws);
    fin2_kernel<<<dim3(1), dim3(64), 0, stream>>>(ws, (float*)d_out);
}

// Round 4
// 34886.908 us; speedup vs baseline: 2.4692x; 1.2944x over previous
//
#include <hip/hip_runtime.h>
#include <math.h>

#define S     128
#define STR   129       // LDS matrix column stride (f64)
#define BB    24
#define RR    64
#define MAXIT 100

// ---- per-block workspace layout (bytes) ----
#define OFF_PC     0          // 128*128 f32
#define OFF_FEATS  65536
#define OFF_CAM    131072
#define OFF_MMETA  196608     // 128 lvl * 128 u32 : out | ent<<8 | exo<<16
#define OFF_MCYC   262144     // rotated cycle node list (int)
#define PER_BLOCK  327680
#define OFF_OBJ    ((size_t)PER_BLOCK * BB)     // 24 * 128 * 8
#define OFF_SPAR   (OFF_OBJ + 24576)            // 24 * 100 * 128 u8
#define OFF_ACC    (OFF_SPAR + 307200)          // accAdv f64, accData f64

// =======================================================================
// Kernel A: feats / cam / data-term / pc init (transposed (d,h) space ==
// raw input layout). Logic identical to validated R1-R3 kernel.
// =======================================================================
__global__ void prep_kernel(const float* __restrict__ s_arc,
                            const float* __restrict__ s_rel,
                            const int* __restrict__ arcs,
                            const int* __restrict__ rels,
                            char* __restrict__ ws) {
    int idx = blockIdx.x * blockDim.x + threadIdx.x;   // b*16384 + d*128 + h
    if (idx >= BB * S * S) return;
    int b  = idx >> 14;
    int dh = idx & (S * S - 1);
    int d  = dh >> 7;
    int h  = dh & (S - 1);

    float sa = s_arc[idx];
    const float* sr = s_rel + (size_t)idx * RR;
    int arc = arcs[b * S + d];
    int rel = rels[b * S + d];
    int rstar = (d >= 1 && h == arc) ? rel : -1;

    float fm = -INFINITY;
    float bestv = -INFINITY;
    float camv = 0.f, datav = 0.f;
    for (int r = 0; r < RR; ++r) {
        float comb = __fadd_rn(sa, sr[r]);
        if (comb > fm) fm = comb;
        float pen = (r == rstar) ? 0.0f : 1.0f;
        float v = __fadd_rn(pen, comb);
        if (v > bestv) { bestv = v; camv = comb; }
        if (rstar >= 0 && r == rel) datav = comb;
    }

    char* base = ws + (size_t)b * PER_BLOCK;
    ((float*)(base + OFF_FEATS))[dh] = fm;
    ((float*)(base + OFF_CAM))[dh]   = camv;
    ((float*)(base + OFF_PC))[dh] = (d >= 1 && h == d - 1) ? 1.0f : 0.0f;

    if (rstar >= 0) {
        double* accData = (double*)(ws + OFF_ACC + 8);
        atomicAdd(accData, (double)datav);
    }
}

// =======================================================================
// Single-wave CLE state (LDS).
// =======================================================================
struct ShState {
    double mat[S * STR];            // 132096 B
    double cyccost[S];
    int parIdx[S], parNew[S], curOrd[S], ordNew[S], o2n[S], outIdx[S],
        slotC[S], inCyc[S], cycA[S], phat[S], spar[S], resA[S],
        hK[S], hC[S];
};

__device__ __forceinline__ int gather2(int lo, int hi, int idx) {
    int a = __builtin_amdgcn_ds_bpermute((idx & 63) * 4, lo);
    int b = __builtin_amdgcn_ds_bpermute((idx & 63) * 4, hi);
    return (idx & 64) ? b : a;
}

// Exact CLE level loop + unwind. Matrix & level-0 parents pre-filled by
// the fused passes. Reference tie-breaks, f64 internals, no barriers.
__device__ void cle_levels(ShState* sh,
                           unsigned int* __restrict__ mMeta,
                           int* __restrict__ mCyc,
                           int* __restrict__ res)
{
    const int lane = threadIdx.x;
    const double DINF = __builtin_inf();

    int n = S, lvl = 0;
    while (true) {
        // ---- pointer doubling, saving jump tables par^(2^r) ----
        int t0a[8], t1a[8];
        t0a[0] = sh->parIdx[lane];
        t1a[0] = sh->parIdx[lane + 64];
#pragma unroll
        for (int r = 0; r < 7; ++r) {
            int u0 = t0a[r], u1 = t1a[r];
            int g0 = gather2(t0a[r], t1a[r], u0 & 127);
            int g1 = gather2(t0a[r], t1a[r], u1 & 127);
            t0a[r + 1] = (u0 < 0) ? -1 : g0;
            t1a[r + 1] = (u1 < 0) ? -1 : g1;
        }
        int jf0 = t0a[7], jf1 = t1a[7];     // par^128 : -1 iff reaches root
        unsigned long long m0 = __ballot(lane >= 1 && lane < n && jf0 >= 0);
        unsigned long long m1 = __ballot(lane + 64 < n && jf1 >= 0);
        if (m0 == 0 && m1 == 0) break;   // no cycle: done
        int sMin = m0 ? ((int)__ffsll((unsigned long long)m0) - 1)
                      : (64 + (int)__ffsll((unsigned long long)m1) - 1);
        int c0 = (sMin < 64) ? __shfl(jf0, sMin) : __shfl(jf1, sMin - 64);

        // ---- dual parallel walk: w_l = par^l(sMin), v_l = par^l(c0) ----
        int w0 = sMin, w1 = sMin, v0 = c0, v1 = c0;
#pragma unroll
        for (int r = 0; r < 6; ++r) {
            int nw0 = gather2(t0a[r], t1a[r], w0);
            int nw1 = gather2(t0a[r], t1a[r], w1);
            int nv0 = gather2(t0a[r], t1a[r], v0);
            int nv1 = gather2(t0a[r], t1a[r], v1);
            bool bit = (lane >> r) & 1;
            w0 = bit ? nw0 : w0;  w1 = bit ? nw1 : w1;
            v0 = bit ? nv0 : v0;  v1 = bit ? nv1 : v1;
        }
        // set1 has l = lane+64: bit 6 always set
        w1 = gather2(t0a[6], t1a[6], w1);
        v1 = gather2(t0a[6], t1a[6], v1);

        // L = cycle length: first l>=1 with v_l == c0
        unsigned long long bl0 = __ballot(lane >= 1 && v0 == c0);
        unsigned long long bl1 = __ballot(v1 == c0);
        int L = bl0 ? ((int)__ffsll((unsigned long long)bl0) - 1)
                    : (64 + (int)__ffsll((unsigned long long)bl1) - 1);
        // mark cycle membership
        if (lane < L) sh->inCyc[v0 & 127] = 1;
        if (lane + 64 < L) sh->inCyc[v1 & 127] = 1;
        // p = entry distance on sMin's path; e = entry node
        int f0 = sh->inCyc[w0 & 127];
        int f1 = sh->inCyc[w1 & 127];
        unsigned long long pb0 = __ballot(f0 != 0);
        unsigned long long pb1 = __ballot(f1 != 0);
        int p = pb0 ? ((int)__ffsll((unsigned long long)pb0) - 1)
                    : (64 + (int)__ffsll((unsigned long long)pb1) - 1);
        int e = (p < 64) ? __shfl(w0, p) : __shfl(w1, p - 64);

        // rotated cycle list starting at e (reference order), slots, costs
        int nxg0 = gather2(w0, w1, lane + 1);
        int nxg1 = gather2(w0, w1, (lane + 65) & 127);
        {
            int l0 = lane;
            if (l0 >= p && l0 < p + L) {
                int i = l0 - p;
                int c = w0 & 127;
                int nn = (i + 1 < L) ? (nxg0 & 127) : e;
                int sc = sh->curOrd[c];
                sh->cycA[i] = c; sh->slotC[i] = sc;
                sh->cyccost[i] = sh->mat[sc * STR + sh->curOrd[nn]];
                mCyc[lvl * S + i] = c;
            }
            int l1 = lane + 64;
            if (l1 >= p && l1 < p + L) {
                int i = l1 - p;
                int c = w1 & 127;
                int nn = (i + 1 < L) ? (nxg1 & 127) : e;
                int sc = sh->curOrd[c];
                sh->cycA[i] = c; sh->slotC[i] = sc;
                sh->cyccost[i] = sh->mat[sc * STR + sh->curOrd[nn]];
                mCyc[lvl * S + i] = c;
            }
        }

        // ---- out list (ascending) via ballot prefix; o2n renumber ----
        int ic0 = sh->inCyc[lane];
        int ic1 = sh->inCyc[lane + 64];
        unsigned long long g0 = __ballot(lane < n && !ic0);
        unsigned long long g1 = __ballot(lane + 64 < n && !ic1);
        int k = __popcll(g0) + __popcll(g1);
        unsigned long long lt = (1ull << lane) - 1ull;
        if (lane < n && !ic0) {
            int pp = __popcll(g0 & lt);
            sh->outIdx[pp] = lane; sh->o2n[lane] = pp;
        }
        if (lane + 64 < n && !ic1) {
            int pp = __popcll(g0) + __popcll(g1 & lt);
            sh->outIdx[pp] = lane + 64; sh->o2n[lane + 64] = pp;
        }
        if (lane == 0) { sh->hK[lvl] = k; sh->hC[lvl] = L; }

        // ---- enter/exit (reads first, writes after: in-order DS pipe) ----
        int supSlot = sh->slotC[0];
        double ev[2], xv[2]; int so[2], np[2];
#pragma unroll
        for (int s2 = 0; s2 < 2; ++s2) {
            int j = lane + s2 * 64;
            ev[s2] = DINF; xv[s2] = DINF; so[s2] = 0; np[s2] = -3;
            if (j < k) {
                int d = sh->outIdx[j];
                int sd = sh->curOrd[d];
                so[s2] = sd;
                // enter: min over cyc of C[out_j, cyc_ci] - cyccost[ci]
                double bv = sh->mat[sh->slotC[0] * STR + sd] - sh->cyccost[0];
                int bi = 0;
                for (int ci = 1; ci < L; ++ci) {
                    double v = sh->mat[sh->slotC[ci] * STR + sd] - sh->cyccost[ci];
                    if (v < bv) { bv = v; bi = ci; }
                }
                ev[s2] = bv;
                // exit: min over cyc of C[cyc_ci, out_j]
                double b2 = sh->mat[sd * STR + sh->slotC[0]];
                int bo = 0;
                for (int ci = 1; ci < L; ++ci) {
                    double v = sh->mat[sd * STR + sh->slotC[ci]];
                    if (v < b2) { b2 = v; bo = ci; }
                }
                xv[s2] = b2;
                sh->ordNew[j] = sd;
                // packed metadata: out | ent<<8 | exo<<16
                mMeta[lvl * S + j] = (unsigned)d | ((unsigned)sh->cycA[bi] << 8)
                                                | ((unsigned)sh->cycA[bo] << 16);
                // incremental par, sup-candidate compare (sound + exact):
                if (j == 0) np[s2] = -1;
                else {
                    int op = sh->parIdx[d];
                    if (sh->inCyc[op]) np[s2] = -2;
                    else {
                        double oldv = sh->mat[sd * STR + sh->curOrd[op]];
                        np[s2] = (b2 < oldv) ? k : sh->o2n[op];
                    }
                }
            }
        }
        // write sup column/row into retired slot of cyc[0]
#pragma unroll
        for (int s2 = 0; s2 < 2; ++s2) {
            int j = lane + s2 * 64;
            if (j < k) {
                sh->mat[supSlot * STR + so[s2]] = ev[s2];
                sh->mat[so[s2] * STR + supSlot] = xv[s2];
            }
        }
        if (lane == 0) { sh->mat[supSlot * STR + supSlot] = DINF; sh->ordNew[k] = supSlot; }

        // sup column par: first-min over ev[0..k-1]
        double rv = (lane < k) ? ev[0] : DINF; int ri = lane;
        {
            double rv1 = (lane + 64 < k) ? ev[1] : DINF;
            if (rv1 < rv) { rv = rv1; ri = lane + 64; }
        }
        for (int off = 32; off; off >>= 1) {
            double ov = __shfl_down(rv, off); int oi = __shfl_down(ri, off);
            if (ov < rv || (ov == rv && oi < ri)) { rv = ov; ri = oi; }
        }
        int supPar = __shfl(ri, 0);

#pragma unroll
        for (int s2 = 0; s2 < 2; ++s2) {
            int j = lane + s2 * 64;
            if (j < k) sh->parNew[j] = np[s2];
        }
        if (lane == 0) sh->parNew[k] = supPar;
        // rescan columns whose old par was in the cycle (exact recompute)
#pragma unroll
        for (int s2 = 0; s2 < 2; ++s2) {
            int j = lane + s2 * 64;
            if (j < k && np[s2] == -2) {
                int sd = so[s2];
                double bv = DINF; int bi = -1;
                for (int h2 = 0; h2 <= k; ++h2) {
                    double v = sh->mat[sd * STR + sh->ordNew[h2]];
                    if (v < bv) { bv = v; bi = h2; }
                }
                sh->parNew[j] = bi;
            }
        }
        // commit
#pragma unroll
        for (int s2 = 0; s2 < 2; ++s2) {
            int i = lane + s2 * 64;
            if (i <= k) { sh->parIdx[i] = sh->parNew[i]; sh->curOrd[i] = sh->ordNew[i]; }
            sh->inCyc[i] = 0;
        }
        n = k + 1; ++lvl;
    }

    // ---- unwind: packed meta, depth-2 named-register prefetch ----
    int r0 = sh->parIdx[lane], r1 = sh->parIdx[lane + 64];
    int l = lvl - 1;
    int mA0=0,mA1=0,cA0=0,cA1=0, mB0=0,mB1=0,cB0=0,cB1=0;
    if (l >= 0) {
        mA0 = mMeta[l*S+lane]; mA1 = mMeta[l*S+lane+64];
        cA0 = mCyc[l*S+lane];  cA1 = mCyc[l*S+lane+64];
    }
    if (l >= 1) {
        mB0 = mMeta[(l-1)*S+lane]; mB1 = mMeta[(l-1)*S+lane+64];
        cB0 = mCyc[(l-1)*S+lane];  cB1 = mCyc[(l-1)*S+lane+64];
    }
#define UNW_STEP(LM0, LM1, LC0, LC1, LVL_)                                    \
    {                                                                         \
        int kl = sh->hK[LVL_], cl = sh->hC[LVL_];                             \
        int hiSup = gather2(r0, r1, kl);                                      \
        int supM = gather2(LM0, LM1, hiSup & 127);                            \
        int u = supM & 255, vE = (supM >> 8) & 255;                           \
        int g0w = gather2(LM0, LM1, r0 & 127);                                \
        int g1w = gather2(LM0, LM1, r1 & 127);                                \
        int gc0 = gather2(LC0, LC1, lane + 1);                                \
        int gc1 = gather2(LC0, LC1, (lane + 65) & 127);                       \
        int c00 = __shfl(LC0, 0);                                             \
        if (lane == 0) sh->resA[0] = -1;                                      \
        if (lane >= 1 && lane < kl)                                           \
            sh->resA[LM0 & 255] = (r0 == kl) ? ((LM0 >> 16) & 255) : (g0w & 255); \
        if (lane + 64 < kl)                                                   \
            sh->resA[LM1 & 255] = (r1 == kl) ? ((LM1 >> 16) & 255) : (g1w & 255); \
        if (lane < cl) {                                                      \
            int c = LC0; int pn = (lane + 1 < cl) ? gc0 : c00;                \
            sh->resA[c & 127] = (c == vE) ? u : pn;                           \
        }                                                                     \
        if (lane + 64 < cl) {                                                 \
            int c = LC1; int pn = (lane + 65 < cl) ? gc1 : c00;               \
            sh->resA[c & 127] = (c == vE) ? u : pn;                           \
        }                                                                     \
        r0 = sh->resA[lane]; r1 = sh->resA[lane + 64];                        \
    }
    while (l >= 0) {
        {
            int lm0 = mA0, lm1 = mA1, lc0 = cA0, lc1 = cA1;
            if (l >= 2) {
                mA0 = mMeta[(l-2)*S+lane]; mA1 = mMeta[(l-2)*S+lane+64];
                cA0 = mCyc[(l-2)*S+lane];  cA1 = mCyc[(l-2)*S+lane+64];
            }
            UNW_STEP(lm0, lm1, lc0, lc1, l)
        }
        --l;
        if (l < 0) break;
        {
            int lm0 = mB0, lm1 = mB1, lc0 = cB0, lc1 = cB1;
            if (l >= 2) {
                mB0 = mMeta[(l-2)*S+lane]; mB1 = mMeta[(l-2)*S+lane+64];
                cB0 = mCyc[(l-2)*S+lane];  cB1 = mCyc[(l-2)*S+lane+64];
            }
            UNW_STEP(lm0, lm1, lc0, lc1, l)
        }
        --l;
    }
#undef UNW_STEP
    res[lane] = r0; res[lane + 64] = r1;
}

// =======================================================================
// Free-running FW kernel: 24 independent blocks x 64 threads.
// Fused column-per-lane passes; stores obj_b[t] and s-parent history.
// =======================================================================
__global__ void __launch_bounds__(64) fw_kernel(char* __restrict__ ws) {
    const int b = blockIdx.x, lane = threadIdx.x;
    char* base = ws + (size_t)b * PER_BLOCK;
    float* pcT = (float*)(base + OFF_PC);
    const float* featsT = (const float*)(base + OFF_FEATS);
    unsigned int* mMeta = (unsigned int*)(base + OFF_MMETA);
    int* mCyc = (int*)(base + OFF_MCYC);
    double* objG = (double*)(ws + OFF_OBJ) + (size_t)b * 128;
    unsigned char* sParG = (unsigned char*)(ws + OFF_SPAR) + (size_t)b * MAXIT * S;

    __shared__ ShState sh;

    for (int t = 0; t < MAXIT; ++t) {
        // ---- pass A: fused pc-update(t-1) + mode-0 fill + level-0 argmin ----
        float gamma = (t > 0) ? (float)(2.0 / (double)(t + 1)) : 0.0f;
#pragma unroll
        for (int c2 = 0; c2 < 2; ++c2) {
            int col = lane + 64 * c2;
            int sp = (t > 0) ? sh.spar[col] : -1;
            float* pcc = pcT + col * S;
            double* mcol = sh.mat + col * STR;
            float bv = __builtin_inff(); int bi = -1;
#pragma unroll
            for (int i = 0; i < 32; ++i) {
                float4 q = ((float4*)pcc)[i];
                float v0 = q.x, v1 = q.y, v2 = q.z, v3 = q.w;
#define PA_ELEM(VV, EE)                                                       \
                {                                                             \
                    int h = i * 4 + EE;                                       \
                    float pv = VV;                                            \
                    if (t > 0) {                                              \
                        float sv = (sp == h) ? 1.0f : 0.0f;                   \
                        pv = __fadd_rn(pv, __fmul_rn(gamma, __fsub_rn(sv, pv))); \
                        VV = pv;                                              \
                    }                                                         \
                    if (h == col || col == 0) mcol[h] = __builtin_inf();      \
                    else {                                                    \
                        float cv = -pv;                                       \
                        if (cv < bv) { bv = cv; bi = h; }                     \
                        mcol[h] = -(double)pv;                                \
                    }                                                         \
                }
                PA_ELEM(v0, 0) PA_ELEM(v1, 1) PA_ELEM(v2, 2) PA_ELEM(v3, 3)
#undef PA_ELEM
                if (t > 0) { q.x=v0; q.y=v1; q.z=v2; q.w=v3; ((float4*)pcc)[i] = q; }
            }
            sh.parIdx[col] = (col == 0) ? -1 : bi;
            sh.curOrd[col] = col;
            sh.inCyc[col] = 0;
        }
        // p_hat = mst(-pc)
        cle_levels(&sh, mMeta, mCyc, sh.phat);

        // ---- pass B: fused obj + grad fill + level-0 argmin ----
        double acc = 0.0;
#pragma unroll
        for (int c2 = 0; c2 < 2; ++c2) {
            int col = lane + 64 * c2;
            int hp = sh.phat[col];
            const float* fc = featsT + col * S;
            const float* pcc = pcT + col * S;
            double* mcol = sh.mat + col * STR;
            float bv = __builtin_inff(); int bi = -1;
#pragma unroll
            for (int i = 0; i < 32; ++i) {
                float4 f4 = ((const float4*)fc)[i];
                float4 p4 = ((const float4*)pcc)[i];
                float fv0=f4.x, fv1=f4.y, fv2=f4.z, fv3=f4.w;
                float pv0=p4.x, pv1=p4.y, pv2=p4.z, pv3=p4.w;
#define PB_ELEM(FV, PV, EE)                                                   \
                {                                                             \
                    int h = i * 4 + EE;                                       \
                    float ph = (hp == h) ? 1.0f : 0.0f;                       \
                    float diff = __fsub_rn(ph, FV);                           \
                    acc += (double)__fmul_rn(diff, PV);                       \
                    if (h == col || col == 0) mcol[h] = __builtin_inf();      \
                    else {                                                    \
                        float g = __fdiv_rn(diff, 24.0f);                     \
                        if (g < bv) { bv = g; bi = h; }                       \
                        mcol[h] = (double)g;                                  \
                    }                                                         \
                }
                PB_ELEM(fv0, pv0, 0) PB_ELEM(fv1, pv1, 1)
                PB_ELEM(fv2, pv2, 2) PB_ELEM(fv3, pv3, 3)
#undef PB_ELEM
            }
            sh.parIdx[col] = (col == 0) ? -1 : bi;
            sh.curOrd[col] = col;
            sh.inCyc[col] = 0;
        }
        for (int off = 32; off; off >>= 1) acc += __shfl_down(acc, off);
        if (lane == 0) objG[t] = acc;

        // s = mst(grad)
        cle_levels(&sh, mMeta, mCyc, sh.spar);
        sParG[t * S + lane]      = (unsigned char)(sh.spar[lane] & 255);
        sParG[t * S + lane + 64] = (unsigned char)(sh.spar[lane + 64] & 255);
    }
}

// =======================================================================
// Finalize: t* = first argmin of mean obj; replay pc to t* (bit-exact
// elementwise f32 recurrence); accumulate loss.
// =======================================================================
__global__ void __launch_bounds__(64) fin_kernel(char* __restrict__ ws) {
    const int b = blockIdx.x, lane = threadIdx.x;
    char* base = ws + (size_t)b * PER_BLOCK;
    const float* camT = (const float*)(base + OFF_CAM);
    const double* objG = (const double*)(ws + OFF_OBJ);
    const unsigned char* sParG =
        (const unsigned char*)(ws + OFF_SPAR) + (size_t)b * MAXIT * S;
    double* accAdv = (double*)(ws + OFF_ACC);

    __shared__ float pcL[S * S];
    __shared__ unsigned char sPL[MAXIT * S];

    // t* : running-min trajectory == first global argmin (strict <)
    double v0 = __builtin_inf(), v1 = __builtin_inf();
    if (lane < MAXIT) {
        double s = 0.0;
        for (int bb = 0; bb < BB; ++bb) s += objG[bb * 128 + lane];
        v0 = s / (double)BB;
    }
    if (lane + 64 < MAXIT) {
        double s = 0.0;
        for (int bb = 0; bb < BB; ++bb) s += objG[bb * 128 + lane + 64];
        v1 = s / (double)BB;
    }
    double bv = v0; int bi = lane;
    if (v1 < bv) { bv = v1; bi = lane + 64; }
    for (int off = 32; off; off >>= 1) {
        double ov = __shfl_down(bv, off); int oi = __shfl_down(bi, off);
        if (ov < bv || (ov == bv && oi < bi)) { bv = ov; bi = oi; }
    }
    int tStar = __shfl(bi, 0);

    // load s history
    for (int wgt = lane; wgt < (MAXIT * S) / 4; wgt += 64)
        ((unsigned int*)sPL)[wgt] = ((const unsigned int*)sParG)[wgt];

    // replay pc from chain to pc_{t*}
    for (int i = 0; i < (S * S) / 64; ++i) {
        int idx = i * 64 + lane;
        int d = idx >> 7, h = idx & (S - 1);
        pcL[idx] = (d >= 1 && h == d - 1) ? 1.0f : 0.0f;
    }
    for (int t = 0; t < tStar; ++t) {
        float gamma = (float)(2.0 / (double)(t + 2));
        for (int d = 0; d < S; ++d) {
            int sp = sPL[t * S + d];
            float p0 = pcL[d * S + lane];
            float p1 = pcL[d * S + lane + 64];
            float sv0 = (sp == lane) ? 1.0f : 0.0f;
            float sv1 = (sp == lane + 64) ? 1.0f : 0.0f;
            pcL[d * S + lane]      = __fadd_rn(p0, __fmul_rn(gamma, __fsub_rn(sv0, p0)));
            pcL[d * S + lane + 64] = __fadd_rn(p1, __fmul_rn(gamma, __fsub_rn(sv1, p1)));
        }
    }
    // loss partial: sum(opt * cam)
    double part = 0.0;
    for (int i = 0; i < (S * S) / 64; ++i) {
        int idx = i * 64 + lane;
        part += (double)__fmul_rn(pcL[idx], camT[idx]);
    }
    for (int off = 32; off; off >>= 1) part += __shfl_down(part, off);
    if (lane == 0) atomicAdd(accAdv, part);
}

__global__ void fin2_kernel(const char* __restrict__ ws, float* __restrict__ out) {
    if (threadIdx.x == 0) {
        const double* acc = (const double*)(ws + OFF_ACC);
        out[0] = (float)((acc[0] - acc[1]) / (double)BB);
    }
}

extern "C" void kernel_launch(void* const* d_in, const int* in_sizes, int n_in,
                              void* d_out, int out_size, void* d_ws, size_t ws_size,
                              hipStream_t stream) {
    const float* s_arc = (const float*)d_in[0];
    const float* s_rel = (const float*)d_in[1];
    const int*   arcs  = (const int*)d_in[2];
    const int*   rels  = (const int*)d_in[3];
    char* ws = (char*)d_ws;

    hipMemsetAsync(ws + OFF_ACC, 0, 16, stream);
    int total = BB * S * S;
    prep_kernel<<<(total + 255) / 256, 256, 0, stream>>>(s_arc, s_rel, arcs, rels, ws);
    fw_kernel<<<dim3(BB), dim3(64), 0, stream>>>(ws);
    fin_kernel<<<dim3(BB), dim3(64), 0, stream>>>(ws);
    fin2_kernel<<<dim3(1), dim3(64), 0, stream>>>(ws, (float*)d_out);
}